// Round 1
// baseline (104.791 us; speedup 1.0000x reference)
//
#include <hip/hip_runtime.h>
#include <hip/hip_bf16.h>
#include <cstdint>

// STFT as im2col GEMM:  C[b,c,t] = sum_n K[c,n] * xpad[b, t*HOP+n]
// M=1026 (pad 1152), N=16*1025 frames, K=1024. bf16 MFMA, fp32 accum.

#define HOP 256
#define NFFT 1024
#define FB 513
#define NT 1025
#define NBATCH 16
#define MCH 1026
#define MP 1152          // padded channel count = 9*128
#define SIGLEN 262144
#define SIGP 263168      // reflect-padded length = SIGLEN + 1024
#define BM 128
#define BT 128
#define BK 64

typedef __attribute__((ext_vector_type(8))) short short8;
typedef __attribute__((ext_vector_type(4))) float f32x4;
typedef unsigned int u32;

__device__ __forceinline__ unsigned short f2bf(float f) {
  u32 u = __float_as_uint(f);
  u = (u + 0x7FFFu + ((u >> 16) & 1u)) >> 16;   // RNE
  return (unsigned short)u;
}

// ---- prologue 1: DFT kernel f32[1026][1024] -> bf16[1152][1024], rows>=1026 zero
__global__ __launch_bounds__(256) void prep_A(const float* __restrict__ kern,
                                              unsigned short* __restrict__ A) {
  size_t i8 = ((size_t)blockIdx.x * 256 + threadIdx.x) * 8;
  int row = (int)(i8 >> 10);
  int col = (int)(i8 & 1023);
  short8 v = {0, 0, 0, 0, 0, 0, 0, 0};
  if (row < MCH) {
    const float* s = kern + ((size_t)row << 10) + col;
#pragma unroll
    for (int e = 0; e < 8; ++e) v[e] = (short)f2bf(s[e]);
  }
  *(short8*)(A + i8) = v;
}

// ---- prologue 2: reflect-pad signal f32[16][262144] -> bf16[16][263168]
__global__ __launch_bounds__(256) void prep_S(const float* __restrict__ sig,
                                              unsigned short* __restrict__ S) {
  size_t i8 = ((size_t)blockIdx.x * 256 + threadIdx.x) * 8;
  int b = (int)(i8 / SIGP);
  int i = (int)(i8 - (size_t)b * SIGP);
  const float* sb = sig + (size_t)b * SIGLEN;
  short8 v;
#pragma unroll
  for (int e = 0; e < 8; ++e) {
    int j = i + e - 512;
    j = (j < 0) ? -j : j;
    j = (j >= SIGLEN) ? (2 * SIGLEN - 2 - j) : j;
    v[e] = (short)f2bf(sb[j]);
  }
  *(short8*)(S + i8) = v;
}

// async 16B global->LDS. LDS dest must be wave-uniform; HW adds lane*16.
__device__ __forceinline__ void async16(void* lds, const void* g) {
  __builtin_amdgcn_global_load_lds(
      (const __attribute__((address_space(1))) u32*)g,
      (__attribute__((address_space(3))) u32*)lds, 16, 0, 0);
}

// ---- main GEMM kernel ----
// Block: 256 thr = 4 waves (2x2), tile BM=128 (c) x BT=128 (t), one batch.
// LDS tiles [128][64] bf16, row stride 128B; XOR-swizzle byte^=((byte>>7)&7)<<4
// applied on READ; global SOURCE pre-swizzled so linear global_load_lds dest works.
__global__ __launch_bounds__(256, 2) void stft_mm(const unsigned short* __restrict__ A,
                                                  const unsigned short* __restrict__ S,
                                                  float* __restrict__ out) {
  __shared__ __align__(16) short sA[BM * BK];
  __shared__ __align__(16) short sB[BT * BK];

  const int tid = threadIdx.x;
  const int lane = tid & 63;
  const int wid = tid >> 6;
  const int wc = wid >> 1;
  const int wt = wid & 1;
  const int lr = lane & 15;
  const int g16 = lane >> 4;
  const int mt = blockIdx.x, tt = blockIdx.y, b = blockIdx.z;
  const int c0 = mt * BM;
  const int t0 = tt * BT;

  const unsigned short* Sb = S + (size_t)b * SIGP;

  f32x4 acc[4][4] = {};

  for (int kt = 0; kt < 16; ++kt) {
    const int n0 = kt * BK;
    // stage A tile: 1024 granules of 16B, 4 per thread
#pragma unroll
    for (int j = 0; j < 4; ++j) {
      const u32 G = (u32)(wid * 256 + j * 64);      // wave-uniform base granule
      u32 p = (G + (u32)lane) * 16u;                // this lane's physical byte
      u32 q = p ^ (((p >> 7) & 7u) << 4);           // logical byte (involution)
      int row = (int)(q >> 7);
      int kk = (int)((q & 127u) >> 1);
      const unsigned short* src = A + ((size_t)(c0 + row) << 10) + (n0 + kk);
      async16((char*)sA + (size_t)G * 16u, src);
    }
    // stage B tile: frames[t][n0..n0+64) = xpad[t*256 + n0 ...]
#pragma unroll
    for (int j = 0; j < 4; ++j) {
      const u32 G = (u32)(wid * 256 + j * 64);
      u32 p = (G + (u32)lane) * 16u;
      u32 q = p ^ (((p >> 7) & 7u) << 4);
      int trow = (int)(q >> 7);
      int kk = (int)((q & 127u) >> 1);
      int s = (t0 + trow) * HOP + n0 + kk;
      s = (s > SIGP - 8) ? (SIGP - 8) : s;          // clamp OOB tail (masked later)
      async16((char*)sB + (size_t)G * 16u, Sb + s);
    }
    __syncthreads();

#pragma unroll
    for (int h = 0; h < 2; ++h) {   // two k-substeps of 32
      short8 af[4], bfv[4];
#pragma unroll
      for (int mi = 0; mi < 4; ++mi) {
        int cl = wc * 64 + mi * 16 + lr;
        u32 a = (u32)(cl * 128 + h * 64 + g16 * 16);
        a ^= ((u32)(cl & 7) << 4);
        af[mi] = *(const short8*)((const char*)sA + a);
      }
#pragma unroll
      for (int ni = 0; ni < 4; ++ni) {
        int tl = wt * 64 + ni * 16 + lr;
        u32 a = (u32)(tl * 128 + h * 64 + g16 * 16);
        a ^= ((u32)(tl & 7) << 4);
        bfv[ni] = *(const short8*)((const char*)sB + a);
      }
#pragma unroll
      for (int mi = 0; mi < 4; ++mi)
#pragma unroll
        for (int ni = 0; ni < 4; ++ni)
          acc[mi][ni] =
              __builtin_amdgcn_mfma_f32_16x16x32_bf16(af[mi], bfv[ni], acc[mi][ni], 0, 0, 0);
    }
    __syncthreads();
  }

  // epilogue: D row=(lane>>4)*4+r is c, col=(lane&15) is t  [guide m89 verified]
  // out[b][f][t][ri], c = ri*513 + f
#pragma unroll
  for (int mi = 0; mi < 4; ++mi) {
    const int cb = c0 + wc * 64 + mi * 16 + g16 * 4;
#pragma unroll
    for (int ni = 0; ni < 4; ++ni) {
      const int t = t0 + wt * 64 + ni * 16 + lr;
      if (t < NT) {
#pragma unroll
        for (int r = 0; r < 4; ++r) {
          const int c = cb + r;
          if (c < MCH) {
            const int ri = (c >= FB) ? 1 : 0;
            const int f = c - ri * FB;
            out[(((size_t)b * FB + f) * NT + t) * 2 + ri] = acc[mi][ni][r];
          }
        }
      }
    }
  }
}

extern "C" void kernel_launch(void* const* d_in, const int* in_sizes, int n_in,
                              void* d_out, int out_size, void* d_ws, size_t ws_size,
                              hipStream_t stream) {
  const float* sig = (const float*)d_in[0];    // (16, 262144) f32
  const float* kern = (const float*)d_in[1];   // (1026, 1024) f32
  float* out = (float*)d_out;                  // (16, 513, 1025, 2) f32

  unsigned short* wsA = (unsigned short*)d_ws;               // 1152*1024 bf16
  unsigned short* wsS = wsA + (size_t)MP * NFFT;             // 16*263168 bf16
  // ws use: (1152*1024 + 16*263168)*2 = 10,780,672 bytes

  prep_A<<<dim3(MP * NFFT / 8 / 256), 256, 0, stream>>>(kern, wsA);
  prep_S<<<dim3(NBATCH * SIGP / 8 / 256), 256, 0, stream>>>(sig, wsS);
  stft_mm<<<dim3(9, 9, NBATCH), 256, 0, stream>>>(wsA, wsS, out);
}

// Round 2
// 68.438 us; speedup vs baseline: 1.5312x; 1.5312x over previous
//
#include <hip/hip_runtime.h>
#include <hip/hip_bf16.h>
#include <cstdint>

// STFT as im2col GEMM:  C[b,c,t] = sum_n K[c,n] * xpad[b, t*HOP+n]
// A rows pair-interleaved: A'[2f+ri] = kernel[ri*513+f]  -> coalesced float2 epilogue.

#define HOP 256
#define NFFT 1024
#define FB 513
#define NT 1025
#define NBATCH 16
#define MCH 1026
#define MP 1152          // padded channel count = 9*128
#define SIGLEN 262144
#define SIGP 263168      // reflect-padded length = SIGLEN + 1024
#define BM 128
#define BT 128
#define BK 64

typedef __attribute__((ext_vector_type(8))) short short8;
typedef __attribute__((ext_vector_type(4))) float f32x4;
typedef unsigned int u32;

__device__ __forceinline__ unsigned short f2bf(float f) {
  u32 u = __float_as_uint(f);
  u = (u + 0x7FFFu + ((u >> 16) & 1u)) >> 16;   // RNE
  return (unsigned short)u;
}

// ---- prologue 1: DFT kernel f32[1026][1024] -> bf16[1152][1024], PAIR-INTERLEAVED:
//      A'[2f+ri][n] = kern[ri*513+f][n];  rows >= 1026 zero.
__global__ __launch_bounds__(256) void prep_A(const float* __restrict__ kern,
                                              unsigned short* __restrict__ A) {
  size_t i8 = ((size_t)blockIdx.x * 256 + threadIdx.x) * 8;
  int row = (int)(i8 >> 10);
  int col = (int)(i8 & 1023);
  short8 v = {0, 0, 0, 0, 0, 0, 0, 0};
  if (row < MCH) {
    int f = row >> 1, ri = row & 1;
    int src_row = ri * FB + f;
    const float* s = kern + ((size_t)src_row << 10) + col;
#pragma unroll
    for (int e = 0; e < 8; ++e) v[e] = (short)f2bf(s[e]);
  }
  *(short8*)(A + i8) = v;
}

// ---- prologue 2: reflect-pad signal f32[16][262144] -> bf16[16][263168]
__global__ __launch_bounds__(256) void prep_S(const float* __restrict__ sig,
                                              unsigned short* __restrict__ S) {
  size_t i8 = ((size_t)blockIdx.x * 256 + threadIdx.x) * 8;
  int b = (int)(i8 / SIGP);
  int i = (int)(i8 - (size_t)b * SIGP);
  const float* sb = sig + (size_t)b * SIGLEN;
  short8 v;
#pragma unroll
  for (int e = 0; e < 8; ++e) {
    int j = i + e - 512;
    j = (j < 0) ? -j : j;
    j = (j >= SIGLEN) ? (2 * SIGLEN - 2 - j) : j;
    v[e] = (short)f2bf(sb[j]);
  }
  *(short8*)(S + i8) = v;
}

// async 16B global->LDS. LDS dest is wave-uniform; HW adds lane*16.
__device__ __forceinline__ void async16(void* lds, const void* g) {
  __builtin_amdgcn_global_load_lds(
      (const __attribute__((address_space(1))) u32*)g,
      (__attribute__((address_space(3))) u32*)lds, 16, 0, 0);
}

// ---- main GEMM kernel ----
// 256 thr = 4 waves (2x2), tile BM=128 (c') x BT=128 (t), one batch per tile.
// LDS tiles [128][64] bf16; XOR-swizzle byte^=((byte>>7)&7)<<4 on READ,
// inverse-swizzled global SOURCE so linear global_load_lds dest works.
__global__ __launch_bounds__(256, 4) void stft_mm(const unsigned short* __restrict__ A,
                                                  const unsigned short* __restrict__ S,
                                                  float* __restrict__ out) {
  __shared__ __align__(16) short sA[BM * BK];
  __shared__ __align__(16) short sB[BT * BK];

  const int tid = threadIdx.x;
  const int lane = tid & 63;
  const int wid = tid >> 6;
  const int wc = wid >> 1;
  const int wt = wid & 1;
  const int lr = lane & 15;
  const int g16 = lane >> 4;

  // bijective XCD-chunk swizzle: nwg = 1296 = 8 * 162
  const int bid = blockIdx.x;
  const int wg = (bid & 7) * 162 + (bid >> 3);
  // mt fastest: 9 consecutive wg share one B window across all A panels
  const int mt = wg % 9;
  const int tb = wg / 9;        // 0..143
  const int tt = tb % 9;
  const int b  = tb / 9;

  const int c0 = mt * BM;
  const int t0 = tt * BT;

  const unsigned short* Sb = S + (size_t)b * SIGP;

  f32x4 acc[4][4] = {};

  for (int kt = 0; kt < 16; ++kt) {
    const int n0 = kt * BK;
    // stage A tile: 1024 granules of 16B, 4 per thread
#pragma unroll
    for (int j = 0; j < 4; ++j) {
      const u32 G = (u32)(wid * 256 + j * 64);      // wave-uniform base granule
      u32 p = (G + (u32)lane) * 16u;                // physical byte in LDS
      u32 q = p ^ (((p >> 7) & 7u) << 4);           // logical byte (involution)
      int row = (int)(q >> 7);
      int kk = (int)((q & 127u) >> 1);
      const unsigned short* src = A + ((size_t)(c0 + row) << 10) + (n0 + kk);
      async16((char*)sA + (size_t)G * 16u, src);
    }
    // stage B tile: frames[t][n0..n0+64) = xpad[t*256 + n0 ...]
#pragma unroll
    for (int j = 0; j < 4; ++j) {
      const u32 G = (u32)(wid * 256 + j * 64);
      u32 p = (G + (u32)lane) * 16u;
      u32 q = p ^ (((p >> 7) & 7u) << 4);
      int trow = (int)(q >> 7);
      int kk = (int)((q & 127u) >> 1);
      int s = (t0 + trow) * HOP + n0 + kk;
      s = (s > SIGP - 8) ? (SIGP - 8) : s;          // clamp OOB tail (masked later)
      async16((char*)sB + (size_t)G * 16u, Sb + s);
    }
    __syncthreads();

#pragma unroll
    for (int h = 0; h < 2; ++h) {   // two k-substeps of 32
      short8 af[4], bfv[4];
#pragma unroll
      for (int mi = 0; mi < 4; ++mi) {
        int cl = wc * 64 + mi * 16 + lr;
        u32 a = (u32)(cl * 128 + h * 64 + g16 * 16);
        a ^= ((u32)(cl & 7) << 4);
        af[mi] = *(const short8*)((const char*)sA + a);
      }
#pragma unroll
      for (int ni = 0; ni < 4; ++ni) {
        int tl = wt * 64 + ni * 16 + lr;
        u32 a = (u32)(tl * 128 + h * 64 + g16 * 16);
        a ^= ((u32)(tl & 7) << 4);
        bfv[ni] = *(const short8*)((const char*)sB + a);
      }
#pragma unroll
      for (int mi = 0; mi < 4; ++mi)
#pragma unroll
        for (int ni = 0; ni < 4; ++ni)
          acc[mi][ni] =
              __builtin_amdgcn_mfma_f32_16x16x32_bf16(af[mi], bfv[ni], acc[mi][ni], 0, 0, 0);
    }
    __syncthreads();
  }

  // epilogue: D row (lane>>4)*4+r = c' (paired channel), col lane&15 = t.
  // c' = 2f+ri  ->  float2 {ri=0,ri=1} store at out[b][f][t][*]; fully coalesced.
#pragma unroll
  for (int mi = 0; mi < 4; ++mi) {
    const int cb = c0 + wc * 64 + mi * 16 + g16 * 4;   // even
    const int f0 = cb >> 1;
#pragma unroll
    for (int ni = 0; ni < 4; ++ni) {
      const int t = t0 + wt * 64 + ni * 16 + lr;
      if (t < NT) {
        if (f0 < FB) {
          *(float2*)(out + ((((size_t)b * FB + f0) * NT + t) << 1)) =
              make_float2(acc[mi][ni][0], acc[mi][ni][1]);
        }
        if (f0 + 1 < FB) {
          *(float2*)(out + ((((size_t)b * FB + f0 + 1) * NT + t) << 1)) =
              make_float2(acc[mi][ni][2], acc[mi][ni][3]);
        }
      }
    }
  }
}

extern "C" void kernel_launch(void* const* d_in, const int* in_sizes, int n_in,
                              void* d_out, int out_size, void* d_ws, size_t ws_size,
                              hipStream_t stream) {
  const float* sig = (const float*)d_in[0];    // (16, 262144) f32
  const float* kern = (const float*)d_in[1];   // (1026, 1024) f32
  float* out = (float*)d_out;                  // (16, 513, 1025, 2) f32

  unsigned short* wsA = (unsigned short*)d_ws;               // 1152*1024 bf16
  unsigned short* wsS = wsA + (size_t)MP * NFFT;             // 16*263168 bf16
  // ws use: (1152*1024 + 16*263168)*2 = 10,780,672 bytes

  prep_A<<<dim3(MP * NFFT / 8 / 256), 256, 0, stream>>>(kern, wsA);
  prep_S<<<dim3(NBATCH * SIGP / 8 / 256), 256, 0, stream>>>(sig, wsS);
  stft_mm<<<dim3(9 * 9 * NBATCH), 256, 0, stream>>>(wsA, wsS, out);
}